// Round 8
// baseline (398.312 us; speedup 1.0000x reference)
//
#include <hip/hip_runtime.h>
#include <hip/hip_bf16.h>

typedef unsigned short u16;
typedef short s8v __attribute__((ext_vector_type(8)));
typedef float f4v __attribute__((ext_vector_type(4)));

#define F 128
#define CIN 1024
#define CMID 512
#define XP 130
#define K9 9216

// gemm LDS element offsets (u16 units)
#define A_ELEMS 8704           // 136 rows * 64
#define B_ELEMS 8192           // 128 rows * 64
#define AOFF(b) ((b) * A_ELEMS)
#define BOFF(b) (2 * A_ELEMS + (b) * B_ELEMS)

__device__ __forceinline__ u16 f2bf(float v) {
    union { float f; unsigned u; } x; x.f = v;
    unsigned r = x.u + 0x7fff + ((x.u >> 16) & 1);
    return (u16)(r >> 16);
}
__device__ __forceinline__ float bf2f(u16 u) {
    union { unsigned u; float f; } x; x.u = ((unsigned)u) << 16; return x.f;
}

__device__ __forceinline__ void gl16(const u16* g, u16* l) {
    __builtin_amdgcn_global_load_lds(
        (const __attribute__((address_space(1))) void*)g,
        (__attribute__((address_space(3))) void*)l,
        16, 0, 0);
}

// anchor base sizes: ratios {0.5,1,2} x scales {8,16,32}
__constant__ float WBASE[9] = {184.f, 368.f, 736.f, 128.f, 256.f, 512.f,  88.f, 176.f, 352.f};
__constant__ float HBASE[9] = { 96.f, 192.f, 384.f, 128.f, 256.f, 512.f, 176.f, 352.f, 704.f};

// ---------------- fused prep: border + transpose + wt + wc + cnt-zero ------
// blocks [0,258): border; [258,4354): transpose; [4354,4866): wt;
// [4866,4994): wc; 4994: zero row-completion counters
__global__ __launch_bounds__(256) void prep_all(
    const float* __restrict__ x, const float* __restrict__ bw,
    const float* __restrict__ cls_w, const float* __restrict__ reg_w,
    u16* __restrict__ xpad, u16* __restrict__ wt, u16* __restrict__ wc,
    int* __restrict__ cnt) {
    __shared__ char ldsraw[18624];       // >= max(64*65*4, 9*1033*2)
    const int b = blockIdx.x;
    const int tid = threadIdx.x;

    if (b < 258) {                       // ---- border zero (vectorized)
        int t = b * 256 + tid;           // 516*128 chunks of 8 u16
        int cell = t >> 7, c8 = (t & 127) * 8;
        int h, w;
        if (cell < 130)      { h = 0;   w = cell; }
        else if (cell < 260) { h = 129; w = cell - 130; }
        else { int rm = cell - 260; h = 1 + (rm >> 1); w = (rm & 1) * 129; }
        s8v z = {};
        *(s8v*)&xpad[(h * XP + w) * CIN + c8] = z;
    } else if (b < 4354) {               // ---- x transpose+pad (float4 reads)
        float (*lds)[65] = (float(*)[65])ldsraw;
        const int b2 = b - 258;
        const int h  = b2 >> 5;
        const int w0 = ((b2 >> 4) & 1) * 64;
        const int c0 = (b2 & 15) * 64;
        {
            const int c  = tid >> 2;     // 0..63
            const int wq = tid & 3;      // 0..3 (16-float segment)
            const float* src = x + (c0 + c) * (F * F) + h * F + w0 + wq * 16;
            #pragma unroll
            for (int k = 0; k < 4; ++k) {
                f4v v = *(const f4v*)(src + k * 4);
                #pragma unroll
                for (int j = 0; j < 4; ++j) lds[c][wq * 16 + k * 4 + j] = v[j];
            }
        }
        __syncthreads();
        {
            const int cs = (tid & 7) * 8;
            #pragma unroll
            for (int pass = 0; pass < 2; ++pass) {
                const int wl = (tid >> 3) + pass * 32;
                s8v v;
                #pragma unroll
                for (int j = 0; j < 8; ++j) v[j] = (short)f2bf(lds[cs + j][wl]);
                *(s8v*)&xpad[((h + 1) * XP + (w0 + wl + 1)) * CIN + c0 + cs] = v;
            }
        }
    } else if (b < 4866) {               // ---- base_w OIHW -> [oc][dydx][c]
        u16* lds = (u16*)ldsraw;         // stride 1033 breaks bank conflicts
        const int oc = b - 4354;
        for (int k = 0; k < 36; ++k) {
            int idx = k * 256 + tid;     // (c,dydx) linear, c-major
            float v = bw[oc * K9 + idx];
            int c = idx / 9, q = idx - c * 9;
            lds[q * 1033 + c] = f2bf(v);
        }
        __syncthreads();
        for (int k = 0; k < 36; ++k) {
            int idx = k * 256 + tid;
            int q = idx >> 10, c = idx & 1023;
            wt[oc * K9 + idx] = lds[q * 1033 + c];
        }
    } else if (b < 4994) {               // ---- combined 1x1 weights
        int t = (b - 4866) * 256 + tid;  // 64*512
        int oc = t >> 9, c = t & 511;
        float v = 0.f;
        if (oc < 18)      v = cls_w[oc * 512 + c];
        else if (oc < 54) v = reg_w[(oc - 18) * 512 + c];
        wc[t] = f2bf(v);
    } else {                             // ---- zero row counters
        if (tid < 128) cnt[tid] = 0;
    }
}

// ---------------- stage 1+2+3 fused ----------------------------------------
// Main: implicit-GEMM 3x3 conv (R5/R7 structure, unchanged). Tail: last block
// of each row-quad (device-scope atomic flag) runs 1x1 convs + softmax +
// proposals for its 128 positions.
__global__ __launch_bounds__(256, 2) void gemm_conv(
    const u16* __restrict__ xpad, const u16* __restrict__ wt,
    const float* __restrict__ bias, u16* __restrict__ rpn,
    const u16* __restrict__ wc, const float* __restrict__ cls_b,
    const float* __restrict__ reg_b, float* __restrict__ out,
    int* __restrict__ cnt) {
    __shared__ u16 smem[2 * A_ELEMS + 2 * B_ELEMS];   // 67584 B
    __shared__ int lastflag;
    const int tid = threadIdx.x;
    const int bid = blockIdx.x;
    const int oc0 = ((bid & 7) >> 1) * 128;
    const int gh  = (bid >> 3) * 2 + (bid & 1);

    const int lane = tid & 63;
    const int wv = tid >> 6;
    const int lm = lane & 15;
    const int lq = lane >> 4;
    const int wm = (wv >> 1) * 64;
    const int wn = (wv & 1) * 64;

    // source-side XOR swizzle: lane L stages data seg (L&7)^((L>>3)&7) of its row
    const int sw = (lane & 7) ^ ((lane >> 3) & 7);
    const u16* pA = xpad + (lane >> 3) * CIN + sw * 8;
    const u16* pB = wt + (size_t)(oc0 + wv * 32 + (lane >> 3)) * K9 + sw * 8;

    f4v acc[4][4] = {};

    auto issueA = [&](int ms) {
        const int dy = ms >> 4, cc = ms & 15;
        const u16* src = pA + ((gh + dy) * XP) * CIN + cc * 64;
        u16* dst = &smem[AOFF(ms & 1)];
        #pragma unroll
        for (int jj = 0; jj < 4; ++jj) {
            const int ci = wv * 4 + jj;
            gl16(src + ci * 8 * CIN, dst + ci * 512);
        }
        if (wv == 0) gl16(src + 16 * 8 * CIN, dst + 16 * 512);  // rows 128..135
    };
    auto issueB = [&](int ms, int dx, int buf) {
        const int dy = ms >> 4, cc = ms & 15;
        const int dydx = dy * 3 + dx;
        const u16* src = pB + dydx * CIN + cc * 64;
        u16* dst = &smem[BOFF(buf) + wv * 32 * 64];
        #pragma unroll
        for (int jj = 0; jj < 4; ++jj)
            gl16(src + jj * 8 * K9, dst + jj * 8 * 64);
    };

    issueA(0);
    issueB(0, 0, 0);
    __syncthreads();

    int t = 0;
    for (int ms = 0; ms < 48; ++ms) {
        const u16* Ab = &smem[AOFF(ms & 1)];
        #pragma unroll
        for (int dx = 0; dx < 3; ++dx, ++t) {
            if (t + 1 < 144) {
                const int msn = (dx == 2) ? ms + 1 : ms;
                const int dxn = (dx == 2) ? 0 : dx + 1;
                issueB(msn, dxn, (t + 1) & 1);
            }
            if (dx == 0 && ms + 1 < 48) issueA(ms + 1);
            const u16* Bb = &smem[BOFF(t & 1)];
            #pragma unroll
            for (int kk = 0; kk < 2; ++kk) {
                const int kseg = kk * 4 + lq;
                s8v af[4], bfr[4];
                #pragma unroll
                for (int i = 0; i < 4; ++i) {
                    const int ra = wm + i * 16 + lm + dx;
                    const int rb = wn + i * 16 + lm;
                    af[i]  = *(const s8v*)&Ab[ra * 64 + ((kseg ^ (ra & 7)) << 3)];
                    bfr[i] = *(const s8v*)&Bb[rb * 64 + ((kseg ^ (rb & 7)) << 3)];
                }
                #pragma unroll
                for (int mi = 0; mi < 4; ++mi)
                    #pragma unroll
                    for (int ni = 0; ni < 4; ++ni)
                        acc[mi][ni] = __builtin_amdgcn_mfma_f32_16x16x32_bf16(
                            af[mi], bfr[ni], acc[mi][ni], 0, 0, 0);
            }
            __syncthreads();
        }
    }

    // epilogue: D[m][n]: m = lq*4+rr (+16mi+wm), n = lm (+16ni+wn)
    #pragma unroll
    for (int ni = 0; ni < 4; ++ni) {
        const int oc = oc0 + wn + ni * 16 + lm;
        const float bv = bias[oc];
        #pragma unroll
        for (int mi = 0; mi < 4; ++mi) {
            #pragma unroll
            for (int rr = 0; rr < 4; ++rr) {
                const int m = wm + mi * 16 + lq * 4 + rr;   // w index
                float v = acc[mi][ni][rr] + bv;
                v = v > 0.f ? v : 0.f;
                rpn[(gh * 128 + m) * CMID + oc] = f2bf(v);
            }
        }
    }

    // ---- fused stage23: last block of this row's quad does it -------------
    __threadfence();
    if (tid == 0) lastflag = atomicAdd(&cnt[gh], 1);
    __syncthreads();
    if (lastflag != 3) return;
    __threadfence();   // acquire: other quads' rpn writes now visible

    float (*vals)[65] = (float(*)[65])smem;   // 128*65*4 = 33280 B, fits
    const u16* rrow = rpn + (size_t)(gh * 128) * CMID;
    f4v a2[2][4] = {};
    #pragma unroll
    for (int k = 0; k < 16; ++k) {
        s8v af0 = *(const s8v*)&rrow[(wv * 32 + lm) * CMID + k * 32 + lq * 8];
        s8v af1 = *(const s8v*)&rrow[(wv * 32 + 16 + lm) * CMID + k * 32 + lq * 8];
        #pragma unroll
        for (int ni = 0; ni < 4; ++ni) {
            s8v bf = *(const s8v*)&wc[(ni * 16 + lm) * CMID + k * 32 + lq * 8];
            a2[0][ni] = __builtin_amdgcn_mfma_f32_16x16x32_bf16(af0, bf, a2[0][ni], 0, 0, 0);
            a2[1][ni] = __builtin_amdgcn_mfma_f32_16x16x32_bf16(af1, bf, a2[1][ni], 0, 0, 0);
        }
    }
    #pragma unroll
    for (int ni = 0; ni < 4; ++ni) {
        const int ch = ni * 16 + lm;
        const float bv = ch < 18 ? cls_b[ch] : (ch < 54 ? reg_b[ch - 18] : 0.f);
        #pragma unroll
        for (int mi = 0; mi < 2; ++mi)
            #pragma unroll
            for (int rr = 0; rr < 4; ++rr)
                vals[wv * 32 + mi * 16 + lq * 4 + rr][ch] = a2[mi][ni][rr] + bv;
    }
    __syncthreads();
    for (int q = tid; q < 1152; q += 256) {
        const int pl = q / 9, a = q - pl * 9;
        const float* v = vals[pl];
        const int ch = 2 * a + 1;
        const int pair = (ch < 9) ? ch + 9 : ch - 9;
        const float score = 1.f / (1.f + expf(v[pair] - v[ch]));
        const float r0 = v[18 + 4 * a], r1 = v[19 + 4 * a];
        const float r2 = v[20 + 4 * a], r3 = v[21 + 4 * a];
        const float wb = WBASE[a], hb = HBASE[a];
        const int p = gh * 128 + pl;
        const int h = p >> 7, w = p & 127;
        float* o = out + (p * 9 + a) * 5;
        o[0] = h * 16.f + wb * r0;
        o[1] = w * 16.f + hb * r1;
        o[2] = wb + expf(r2);
        o[3] = hb + expf(r3);
        o[4] = score;
    }
}

extern "C" void kernel_launch(void* const* d_in, const int* in_sizes, int n_in,
                              void* d_out, int out_size, void* d_ws, size_t ws_size,
                              hipStream_t stream) {
    const float* x      = (const float*)d_in[0];
    const float* base_w = (const float*)d_in[1];
    const float* base_b = (const float*)d_in[2];
    const float* cls_w  = (const float*)d_in[3];
    const float* cls_b  = (const float*)d_in[4];
    const float* reg_w  = (const float*)d_in[5];
    const float* reg_b  = (const float*)d_in[6];
    float* out = (float*)d_out;

    char* ws = (char*)d_ws;
    u16* xpad = (u16*)ws;                                   // 34,611,200 B
    u16* wt   = (u16*)(ws + 34611200);                      //  9,437,184 B
    u16* wc   = (u16*)(ws + 34611200 + 9437184);            //     65,536 B
    u16* rpn  = (u16*)(ws + 34611200 + 9437184 + 65536);    // 16,777,216 B
    int* cnt  = (int*)(ws + 34611200 + 9437184 + 65536 + 16777216); // 512 B

    prep_all<<<4995, 256, 0, stream>>>(x, base_w, cls_w, reg_w, xpad, wt, wc, cnt);
    gemm_conv<<<512, 256, 0, stream>>>(xpad, wt, base_b, rpn,
                                       wc, cls_b, reg_b, out, cnt);
}

// Round 9
// 259.600 us; speedup vs baseline: 1.5343x; 1.5343x over previous
//
#include <hip/hip_runtime.h>
#include <hip/hip_bf16.h>

typedef unsigned short u16;
typedef short s8v __attribute__((ext_vector_type(8)));
typedef float f4v __attribute__((ext_vector_type(4)));

#define F 128
#define CIN 1024
#define CMID 512
#define XP 130
#define K9 9216

// gemm LDS element offsets (u16 units)
#define A_ELEMS 8704           // 136 rows * 64
#define B_ELEMS 8192           // 128 rows * 64
#define AOFF(b) ((b) * A_ELEMS)
#define BOFF(b) (2 * A_ELEMS + (b) * B_ELEMS)

__device__ __forceinline__ u16 f2bf(float v) {
    union { float f; unsigned u; } x; x.f = v;
    unsigned r = x.u + 0x7fff + ((x.u >> 16) & 1);
    return (u16)(r >> 16);
}
__device__ __forceinline__ float bf2f(u16 u) {
    union { unsigned u; float f; } x; x.u = ((unsigned)u) << 16; return x.f;
}

__device__ __forceinline__ void gl16(const u16* g, u16* l) {
    __builtin_amdgcn_global_load_lds(
        (const __attribute__((address_space(1))) void*)g,
        (__attribute__((address_space(3))) void*)l,
        16, 0, 0);
}

// anchor base sizes: ratios {0.5,1,2} x scales {8,16,32}
__constant__ float WBASE[9] = {184.f, 368.f, 736.f, 128.f, 256.f, 512.f,  88.f, 176.f, 352.f};
__constant__ float HBASE[9] = { 96.f, 192.f, 384.f, 128.f, 256.f, 512.f, 176.f, 352.f, 704.f};

// ---------------- fused prep ------------------------------------------------
// blocks [0,512): transpose (h, c-quarter); [512,1024): wt; [1024,1282): border;
// [1282,1410): wc
__global__ __launch_bounds__(256) void prep_all(
    const float* __restrict__ x, const float* __restrict__ bw,
    const float* __restrict__ cls_w, const float* __restrict__ reg_w,
    u16* __restrict__ xpad, u16* __restrict__ wt, u16* __restrict__ wc) {
    __shared__ char ldsraw[128 * 65 * 4];   // 33280 B (wt needs 18594)
    const int b = blockIdx.x;
    const int tid = threadIdx.x;

    if (b < 512) {                       // ---- x transpose+pad, fat blocks
        float (*lds)[65] = (float(*)[65])ldsraw;   // [w][c] per 64-c chunk
        const int h  = b >> 2;
        const int c0 = (b & 3) * 256;
        #pragma unroll 1
        for (int cc = 0; cc < 4; ++cc) {
            const int cb = c0 + cc * 64;
            {   // read: 512B-contiguous f4v per half-wave, scatter to [w][c]
                const int w4 = (tid & 31) * 4;
                const int cl = tid >> 5;         // 0..7
                #pragma unroll
                for (int p = 0; p < 8; ++p) {
                    const int c = p * 8 + cl;
                    f4v v = *(const f4v*)&x[(cb + c) * (F * F) + h * F + w4];
                    #pragma unroll
                    for (int k = 0; k < 4; ++k) lds[w4 + k][c] = v[k];
                }
            }
            __syncthreads();
            {   // write: 8 scalar LDS reads (2-way, free) -> s8v store
                const int cs = (tid & 7) * 8;
                const int wb = tid >> 3;         // 0..31
                #pragma unroll
                for (int p = 0; p < 4; ++p) {
                    const int w = p * 32 + wb;
                    s8v v;
                    #pragma unroll
                    for (int j = 0; j < 8; ++j) v[j] = (short)f2bf(lds[w][cs + j]);
                    *(s8v*)&xpad[((h + 1) * XP + (w + 1)) * CIN + cb + cs] = v;
                }
            }
            __syncthreads();
        }
    } else if (b < 1024) {               // ---- base_w OIHW -> [oc][dydx][c]
        u16* lds = (u16*)ldsraw;         // stride 1033 breaks bank conflicts
        const int oc = b - 512;
        for (int k = 0; k < 36; ++k) {
            int idx = k * 256 + tid;     // (c,dydx) linear, c-major
            float v = bw[oc * K9 + idx];
            int c = idx / 9, q = idx - c * 9;
            lds[q * 1033 + c] = f2bf(v);
        }
        __syncthreads();
        for (int k = 0; k < 36; ++k) {
            int idx = k * 256 + tid;
            int q = idx >> 10, c = idx & 1023;
            wt[oc * K9 + idx] = lds[q * 1033 + c];
        }
    } else if (b < 1282) {               // ---- border zero (vectorized)
        int t = (b - 1024) * 256 + tid;  // 516*128 chunks of 8 u16
        int cell = t >> 7, c8 = (t & 127) * 8;
        int h, w;
        if (cell < 130)      { h = 0;   w = cell; }
        else if (cell < 260) { h = 129; w = cell - 130; }
        else { int rm = cell - 260; h = 1 + (rm >> 1); w = (rm & 1) * 129; }
        s8v z = {};
        *(s8v*)&xpad[(h * XP + w) * CIN + c8] = z;
    } else {                             // ---- combined 1x1 weights
        int t = (b - 1282) * 256 + tid;  // 64*512
        int oc = t >> 9, c = t & 511;
        float v = 0.f;
        if (oc < 18)      v = cls_w[oc * 512 + c];
        else if (oc < 54) v = reg_w[(oc - 18) * 512 + c];
        wc[t] = f2bf(v);
    }
}

// ---------------- stage 1: implicit-GEMM 3x3 conv + bias + ReLU ------------
// (R7 structure verbatim — measured 138 us, MfmaUtil 50%)
__global__ __launch_bounds__(256, 2) void gemm_conv(
    const u16* __restrict__ xpad, const u16* __restrict__ wt,
    const float* __restrict__ bias, u16* __restrict__ rpn) {
    __shared__ u16 smem[2 * A_ELEMS + 2 * B_ELEMS];   // 67584 B
    const int tid = threadIdx.x;
    const int bid = blockIdx.x;
    const int oc0 = ((bid & 7) >> 1) * 128;
    const int gh  = (bid >> 3) * 2 + (bid & 1);

    const int lane = tid & 63;
    const int wv = tid >> 6;
    const int lm = lane & 15;
    const int lq = lane >> 4;
    const int wm = (wv >> 1) * 64;
    const int wn = (wv & 1) * 64;

    // source-side XOR swizzle: lane L stages data seg (L&7)^((L>>3)&7) of its row
    const int sw = (lane & 7) ^ ((lane >> 3) & 7);
    const u16* pA = xpad + (lane >> 3) * CIN + sw * 8;
    const u16* pB = wt + (size_t)(oc0 + wv * 32 + (lane >> 3)) * K9 + sw * 8;

    f4v acc[4][4] = {};

    auto issueA = [&](int ms) {
        const int dy = ms >> 4, cc = ms & 15;
        const u16* src = pA + ((gh + dy) * XP) * CIN + cc * 64;
        u16* dst = &smem[AOFF(ms & 1)];
        #pragma unroll
        for (int jj = 0; jj < 4; ++jj) {
            const int ci = wv * 4 + jj;
            gl16(src + ci * 8 * CIN, dst + ci * 512);
        }
        if (wv == 0) gl16(src + 16 * 8 * CIN, dst + 16 * 512);  // rows 128..135
    };
    auto issueB = [&](int ms, int dx, int buf) {
        const int dy = ms >> 4, cc = ms & 15;
        const int dydx = dy * 3 + dx;
        const u16* src = pB + dydx * CIN + cc * 64;
        u16* dst = &smem[BOFF(buf) + wv * 32 * 64];
        #pragma unroll
        for (int jj = 0; jj < 4; ++jj)
            gl16(src + jj * 8 * K9, dst + jj * 8 * 64);
    };

    issueA(0);
    issueB(0, 0, 0);
    __syncthreads();

    int t = 0;
    for (int ms = 0; ms < 48; ++ms) {
        const u16* Ab = &smem[AOFF(ms & 1)];
        #pragma unroll
        for (int dx = 0; dx < 3; ++dx, ++t) {
            if (t + 1 < 144) {
                const int msn = (dx == 2) ? ms + 1 : ms;
                const int dxn = (dx == 2) ? 0 : dx + 1;
                issueB(msn, dxn, (t + 1) & 1);
            }
            if (dx == 0 && ms + 1 < 48) issueA(ms + 1);
            const u16* Bb = &smem[BOFF(t & 1)];
            #pragma unroll
            for (int kk = 0; kk < 2; ++kk) {
                const int kseg = kk * 4 + lq;
                s8v af[4], bfr[4];
                #pragma unroll
                for (int i = 0; i < 4; ++i) {
                    const int ra = wm + i * 16 + lm + dx;
                    const int rb = wn + i * 16 + lm;
                    af[i]  = *(const s8v*)&Ab[ra * 64 + ((kseg ^ (ra & 7)) << 3)];
                    bfr[i] = *(const s8v*)&Bb[rb * 64 + ((kseg ^ (rb & 7)) << 3)];
                }
                #pragma unroll
                for (int mi = 0; mi < 4; ++mi)
                    #pragma unroll
                    for (int ni = 0; ni < 4; ++ni)
                        acc[mi][ni] = __builtin_amdgcn_mfma_f32_16x16x32_bf16(
                            af[mi], bfr[ni], acc[mi][ni], 0, 0, 0);
            }
            __syncthreads();
        }
    }

    #pragma unroll
    for (int ni = 0; ni < 4; ++ni) {
        const int oc = oc0 + wn + ni * 16 + lm;
        const float bv = bias[oc];
        #pragma unroll
        for (int mi = 0; mi < 4; ++mi) {
            #pragma unroll
            for (int rr = 0; rr < 4; ++rr) {
                const int m = wm + mi * 16 + lq * 4 + rr;   // w index
                float v = acc[mi][ni][rr] + bv;
                v = v > 0.f ? v : 0.f;
                rpn[(gh * 128 + m) * CMID + oc] = f2bf(v);
            }
        }
    }
}

// ---------------- stage 2+3: 1x1 convs (MFMA, K-split) + softmax + proposals
// (R7 verbatim) 1024 blocks x 16 rows; 4 waves K-split; LDS reduce.
__global__ __launch_bounds__(256) void stage23(
    const u16* __restrict__ rpn, const u16* __restrict__ wc,
    const float* __restrict__ cls_b, const float* __restrict__ reg_b,
    float* __restrict__ out) {
    __shared__ float part[4][16][65];
    const int tid = threadIdx.x, lane = tid & 63, wv = tid >> 6;
    const int lm = lane & 15, lq = lane >> 4;
    const int m0 = blockIdx.x * 16;

    f4v acc[4] = {};
    const u16* arow = rpn + (m0 + lm) * CMID + wv * 128 + lq * 8;
    const u16* brow = wc + lm * CMID + wv * 128 + lq * 8;
    #pragma unroll
    for (int k = 0; k < 4; ++k) {
        s8v af = *(const s8v*)(arow + k * 32);
        #pragma unroll
        for (int ni = 0; ni < 4; ++ni) {
            s8v bf = *(const s8v*)(brow + ni * 16 * CMID + k * 32);
            acc[ni] = __builtin_amdgcn_mfma_f32_16x16x32_bf16(af, bf, acc[ni], 0, 0, 0);
        }
    }
    #pragma unroll
    for (int ni = 0; ni < 4; ++ni)
        #pragma unroll
        for (int rr = 0; rr < 4; ++rr)
            part[wv][lq * 4 + rr][ni * 16 + lm] = acc[ni][rr];
    __syncthreads();

    float vsum[4];
    const int col = tid & 63, rb = tid >> 6;
    const float bv = col < 18 ? cls_b[col] : (col < 54 ? reg_b[col - 18] : 0.f);
    #pragma unroll
    for (int rr = 0; rr < 4; ++rr) {
        const int row = rb * 4 + rr;
        vsum[rr] = part[0][row][col] + part[1][row][col]
                 + part[2][row][col] + part[3][row][col] + bv;
    }
    __syncthreads();
    #pragma unroll
    for (int rr = 0; rr < 4; ++rr)
        part[0][rb * 4 + rr][col] = vsum[rr];
    __syncthreads();

    if (tid < 144) {
        const int pl = tid / 9, a = tid - pl * 9;
        const float* v = part[0][pl];
        const int ch = 2 * a + 1;
        const int pair = (ch < 9) ? ch + 9 : ch - 9;
        const float score = 1.f / (1.f + expf(v[pair] - v[ch]));
        const float r0 = v[18 + 4 * a], r1 = v[19 + 4 * a];
        const float r2 = v[20 + 4 * a], r3 = v[21 + 4 * a];
        const float wb = WBASE[a], hb = HBASE[a];
        const int p = m0 + pl;
        const int h = p >> 7, w = p & 127;
        float* o = out + (p * 9 + a) * 5;
        o[0] = h * 16.f + wb * r0;
        o[1] = w * 16.f + hb * r1;
        o[2] = wb + expf(r2);
        o[3] = hb + expf(r3);
        o[4] = score;
    }
}

extern "C" void kernel_launch(void* const* d_in, const int* in_sizes, int n_in,
                              void* d_out, int out_size, void* d_ws, size_t ws_size,
                              hipStream_t stream) {
    const float* x      = (const float*)d_in[0];
    const float* base_w = (const float*)d_in[1];
    const float* base_b = (const float*)d_in[2];
    const float* cls_w  = (const float*)d_in[3];
    const float* cls_b  = (const float*)d_in[4];
    const float* reg_w  = (const float*)d_in[5];
    const float* reg_b  = (const float*)d_in[6];
    float* out = (float*)d_out;

    char* ws = (char*)d_ws;
    u16* xpad = (u16*)ws;                                   // 34,611,200 B
    u16* wt   = (u16*)(ws + 34611200);                      //  9,437,184 B
    u16* wc   = (u16*)(ws + 34611200 + 9437184);            //     65,536 B
    u16* rpn  = (u16*)(ws + 34611200 + 9437184 + 65536);    // 16,777,216 B

    prep_all<<<1410, 256, 0, stream>>>(x, base_w, cls_w, reg_w, xpad, wt, wc);
    gemm_conv<<<512, 256, 0, stream>>>(xpad, wt, base_b, rpn);
    stage23<<<1024, 256, 0, stream>>>(rpn, wc, cls_b, reg_b, out);
}